// Round 2
// baseline (2914.894 us; speedup 1.0000x reference)
//
#include <hip/hip_runtime.h>
#include <hip/hip_bf16.h>

// NodeProcessor: per-edge bilinear messages -> gated scatter-add -> BN -> +x
// Sizes: N=10000 nodes, E=160000 edges, S1=64, V1=32, S2=16, V2=8, SOUT=96.
// All float tensors are FLOAT32 (per reference); edge_index int32.
//
// Decomposition:
//   GEMM-S: A_s[e,k] (k<1024: s1[a]*s2[b]; k>=1024: dot3(v1[a],v2[b]))
//           @ W_S[k,c] (c<96). Scales 1/sqrt(1280) and 1/sqrt(3) folded into W_S.
//   GEMM-V: A_v[p][e,k] (k<512: s1[a]*v2[b,p]; <1024: v1[a,p]*s2[b];
//           >=1024: cross(v1[a],v2[b])[p]) @ W_V[k,c] (c<32). Scales folded.
// Then silu/sigmoid gating, atomic scatter to node accumulators (f32 in ws),
// BN stats via atomics, finalize writes f32 out.

#define NNODES 10000
#define NEDGES 160000
#define TE 64

typedef unsigned short u16;

__device__ __forceinline__ float b2f(u16 u) {
  union { unsigned int i; float f; } v; v.i = ((unsigned int)u) << 16; return v.f;
}
__device__ __forceinline__ u16 f2b(float f) {  // RNE f32->bf16
  union { float f; unsigned int i; } v; v.f = f;
  unsigned int r = v.i + 0x7FFFu + ((v.i >> 16) & 1u);
  return (u16)(r >> 16);
}

#define INVF  0.02795084971874737f   // 1/sqrt(1280)
#define INV3  0.5773502691896258f    // 1/sqrt(3)
#define INV2  0.7071067811865476f    // 1/sqrt(2)

// ---- prep: pack all 5 W tensors with scales folded in --------------------
__global__ void pack_kernel(const float* __restrict__ W_ss, const float* __restrict__ W_vv_s,
                            const float* __restrict__ W_sv, const float* __restrict__ W_vs,
                            const float* __restrict__ W_vv_v,
                            float* __restrict__ W_S, float* __restrict__ W_V) {
  int t = blockIdx.x * 256 + threadIdx.x;
  if (t < 122880) { // W_S: 1280 x 96 (rows: 1024 ss + 256 vv_s)
    float v = (t < 98304) ? W_ss[t] * INVF
                          : W_vv_s[t - 98304] * (INVF * INV3);
    W_S[t] = v;
  }
  int u = t - 122880;
  if (u >= 0 && u < 40960) { // W_V: 1280 x 32 (rows: 512 sv + 512 vs + 256 cross)
    int k = u >> 5;
    float v;
    if (k < 512)       v = W_sv[u] * INVF;
    else if (k < 1024) v = W_vs[u - 16384] * INVF;
    else               v = W_vv_v[u - 32768] * (INVF * INV2);
    W_V[u] = v;
  }
}

__global__ void zero_kernel(float* __restrict__ p, int n) {
  int t = blockIdx.x * 256 + threadIdx.x;
  if (t < n) p[t] = 0.f;
}

// ---- edge kernel: 64 edges/block, 256 threads ----------------------------
__global__ __launch_bounds__(256, 2) void edge_kernel(
    const float* __restrict__ x, const float* __restrict__ ea,
    const int* __restrict__ eidx,
    const float* __restrict__ W_S, const float* __restrict__ W_V,
    float* __restrict__ s_n, float* __restrict__ v_n) {
  __shared__ int idxL[TE];
  __shared__ u16 s1b[TE][64];
  __shared__ u16 v1b[TE][96];
  __shared__ u16 s2b[TE][16];
  __shared__ u16 v2b[TE][24];
  __shared__ __align__(16) float Af[TE * 112]; // S uses [e][68-stride], V uses [e][p*36+kk]

  const int tid = threadIdx.x;
  const int eb = blockIdx.x * TE;
  if (tid < TE) idxL[tid] = eidx[eb + tid];
  __syncthreads();

  // stage features (f32 -> bf16) to LDS
  for (int t = tid; t < TE * 160; t += 256) {
    int e = t / 160, j = t - e * 160;
    u16 v = f2b(x[idxL[e] * 160 + j]);
    if (j < 64) s1b[e][j] = v; else v1b[e][j - 64] = v;
  }
  for (int t = tid; t < TE * 40; t += 256) {
    int e = t / 40, j = t - e * 40;
    u16 v = f2b(ea[(eb + e) * 40 + j]);
    if (j < 16) s2b[e][j] = v; else v2b[e][j - 16] = v;
  }

  const int te = tid >> 5, tc = tid & 31;
  const int e0 = te * 8;
  float gate8[8];

  // ================= GEMM-S: s_out[e][c], thread owns 8e x {tc,tc+32,tc+64}
  float acc[8][3];
#pragma unroll
  for (int ee = 0; ee < 8; ee++) { acc[ee][0] = acc[ee][1] = acc[ee][2] = 0.f; }

  for (int k0 = 0; k0 < 1280; k0 += 64) {
    __syncthreads();
    for (int t = tid; t < TE * 64; t += 256) {
      int kk = t & 63, e = t >> 6;
      int k = k0 + kk;
      float v;
      if (k < 1024) {
        int a = k >> 4, b = k & 15;
        v = b2f(s1b[e][a]) * b2f(s2b[e][b]);
      } else {
        int q = k - 1024, a = q >> 3, b = q & 7;
        v = b2f(v1b[e][a*3+0]) * b2f(v2b[e][b*3+0]) +
            b2f(v1b[e][a*3+1]) * b2f(v2b[e][b*3+1]) +
            b2f(v1b[e][a*3+2]) * b2f(v2b[e][b*3+2]);   // scale folded in W_S
      }
      Af[e * 68 + kk] = v;
    }
    __syncthreads();
    for (int kk = 0; kk < 64; kk += 4) {
      float a4[8][4];
#pragma unroll
      for (int ee = 0; ee < 8; ee++) {
        float4 t4 = *(const float4*)&Af[(e0 + ee) * 68 + kk];
        a4[ee][0] = t4.x; a4[ee][1] = t4.y; a4[ee][2] = t4.z; a4[ee][3] = t4.w;
      }
#pragma unroll
      for (int j = 0; j < 4; j++) {
        const float* wr = W_S + (k0 + kk + j) * 96 + tc;
        float w0 = wr[0], w1 = wr[32], w2 = wr[64];
#pragma unroll
        for (int ee = 0; ee < 8; ee++) {
          float a = a4[ee][j];
          acc[ee][0] += a * w0; acc[ee][1] += a * w1; acc[ee][2] += a * w2;
        }
      }
    }
  }

  // finalize S: silu -> atomic scatter; sigmoid gate -> registers
#pragma unroll
  for (int ee = 0; ee < 8; ee++) {
    int e = e0 + ee;
    int ibase = idxL[e] * 64;
    float v0 = acc[ee][0], v1 = acc[ee][1], v2 = acc[ee][2];
    atomicAdd(&s_n[ibase + tc],      v0 / (1.f + expf(-v0)));
    atomicAdd(&s_n[ibase + tc + 32], v1 / (1.f + expf(-v1)));
    gate8[ee] = 1.f / (1.f + expf(-v2));
  }

  // ================= GEMM-V: v_out[e][c][p], thread owns 8e x c=tc x 3p
  float accv[8][3];
#pragma unroll
  for (int ee = 0; ee < 8; ee++) { accv[ee][0] = accv[ee][1] = accv[ee][2] = 0.f; }

  for (int k0 = 0; k0 < 1280; k0 += 32) {
    __syncthreads();
    // build A_v chunk: layout [e][p*36 + kk], row stride 112 (16B aligned)
    for (int t = tid; t < TE * 96; t += 256) {
      int kk = t & 31, e = (t >> 5) & 63, p = t >> 11;
      int k = k0 + kk;
      float v;
      if (k < 512) {
        int a = k >> 3, b = k & 7;
        v = b2f(s1b[e][a]) * b2f(v2b[e][b*3 + p]);
      } else if (k < 1024) {
        int q = k - 512, a = q >> 4, b = q & 15;
        v = b2f(v1b[e][a*3 + p]) * b2f(s2b[e][b]);
      } else {
        int q = k - 1024, a = q >> 3, b = q & 7;
        int p1 = (p == 2) ? 0 : p + 1;
        int p2 = (p == 0) ? 2 : p - 1;
        v = b2f(v1b[e][a*3 + p1]) * b2f(v2b[e][b*3 + p2]) -
            b2f(v1b[e][a*3 + p2]) * b2f(v2b[e][b*3 + p1]);  // scale folded in W_V
      }
      Af[e * 112 + p * 36 + kk] = v;
    }
    __syncthreads();
    for (int kk = 0; kk < 32; kk += 4) {
      float w[4];
#pragma unroll
      for (int j = 0; j < 4; j++) w[j] = W_V[(k0 + kk + j) * 32 + tc];
#pragma unroll
      for (int ee = 0; ee < 8; ee++) {
#pragma unroll
        for (int p = 0; p < 3; p++) {
          float4 av = *(const float4*)&Af[(e0 + ee) * 112 + p * 36 + kk];
          accv[ee][p] += av.x * w[0];
          accv[ee][p] += av.y * w[1];
          accv[ee][p] += av.z * w[2];
          accv[ee][p] += av.w * w[3];
        }
      }
    }
  }

  // finalize V: gate and scatter
#pragma unroll
  for (int ee = 0; ee < 8; ee++) {
    int e = e0 + ee;
    float g = gate8[ee];
    int ibase = idxL[e] * 96 + tc * 3;
#pragma unroll
    for (int p = 0; p < 3; p++)
      atomicAdd(&v_n[ibase + p], accv[ee][p] * g);
  }
}

// ---- BN stats: per-channel sums over nodes -------------------------------
__global__ void stats_kernel(const float* __restrict__ s_n, const float* __restrict__ v_n,
                             float* __restrict__ stats) {
  int b = blockIdx.x, tid = threadIdx.x;
  int r0 = b * 100;
  int c = tid & 63, rg = tid >> 6;         // 4 row-groups
  float s = 0.f, sq = 0.f;
  for (int r = r0 + rg; r < r0 + 100; r += 4) {
    float v = s_n[r * 64 + c];
    s += v; sq += v * v;
  }
  atomicAdd(&stats[c], s);
  atomicAdd(&stats[64 + c], sq);
  int c2 = tid & 31, rg2 = tid >> 5;       // 8 row-groups
  float vn = 0.f;
  for (int r = r0 + rg2; r < r0 + 100; r += 8) {
    const float* vp = &v_n[r * 96 + c2 * 3];
    vn += vp[0] * vp[0] + vp[1] * vp[1] + vp[2] * vp[2];
  }
  atomicAdd(&stats[128 + c2], vn);
}

// ---- finalize: BN + residual, write f32 ----------------------------------
__global__ void finalize_kernel(const float* __restrict__ s_n, const float* __restrict__ v_n,
                                const float* __restrict__ stats,
                                const float* __restrict__ x,
                                const float* __restrict__ bw_s, const float* __restrict__ bb_s,
                                const float* __restrict__ bw_v,
                                float* __restrict__ out) {
  int t = blockIdx.x * 256 + threadIdx.x;
  if (t >= NNODES * 160) return;
  int n = t / 160, j = t - n * 160;
  float xv = x[t];
  float r;
  if (j < 64) {
    float mu  = stats[j] * (1.f / NNODES);
    float var = stats[64 + j] * (1.f / NNODES) - mu * mu;
    var = fmaxf(var, 0.f);
    float v = s_n[n * 64 + j];
    r = (v - mu) * rsqrtf(var + 1e-5f) * bw_s[j] + bb_s[j];
  } else {
    int q = j - 64;
    int c = q / 3;
    float vn = stats[128 + c] * (1.f / (3.f * NNODES));
    float v = v_n[n * 96 + q];
    r = v * rsqrtf(vn + 1e-5f) * bw_v[c];
  }
  out[t] = r + xv;
}

extern "C" void kernel_launch(void* const* d_in, const int* in_sizes, int n_in,
                              void* d_out, int out_size, void* d_ws, size_t ws_size,
                              hipStream_t stream) {
  const float* x      = (const float*)d_in[0];
  const float* ea     = (const float*)d_in[1];
  const float* W_ss   = (const float*)d_in[2];
  const float* W_vv_s = (const float*)d_in[3];
  const float* W_sv   = (const float*)d_in[4];
  const float* W_vs   = (const float*)d_in[5];
  const float* W_vv_v = (const float*)d_in[6];
  const float* bw_s   = (const float*)d_in[7];
  const float* bb_s   = (const float*)d_in[8];
  const float* bw_v   = (const float*)d_in[9];
  const int* eidx     = (const int*)d_in[10];
  float* out = (float*)d_out;

  float* ws    = (float*)d_ws;
  float* W_S   = ws;              // 122880
  float* W_V   = ws + 122880;     // 40960
  float* s_n   = ws + 163840;     // 640000
  float* v_n   = ws + 803840;     // 960000
  float* stats = ws + 1763840;    // 160
  // zero region: s_n + v_n + stats = 1600160 floats (contiguous)

  pack_kernel<<<640, 256, 0, stream>>>(W_ss, W_vv_s, W_sv, W_vs, W_vv_v, W_S, W_V);
  zero_kernel<<<(1600160 + 255) / 256, 256, 0, stream>>>(s_n, 1600160);
  edge_kernel<<<NEDGES / TE, 256, 0, stream>>>(x, ea, eidx, W_S, W_V, s_n, v_n);
  stats_kernel<<<100, 256, 0, stream>>>(s_n, v_n, stats);
  finalize_kernel<<<(NNODES * 160 + 255) / 256, 256, 0, stream>>>(
      s_n, v_n, stats, x, bw_s, bb_s, bw_v, out);
}

// Round 3
// 496.715 us; speedup vs baseline: 5.8683x; 5.8683x over previous
//
#include <hip/hip_runtime.h>
#include <hip/hip_bf16.h>

// NodeProcessor via MFMA. Per block: 64 edges.
//   GEMM-S: A_s[64e x 1280k] (bf16, built in LDS) @ W_S[1280 x 96]  (packed bf16)
//   GEMM-V: A_v[192(p,e) x 1280k] @ W_V[1280 x 32]
// mfma_f32_16x16x32_bf16; A-frag: A[m=lane&15][k=(lane>>4)*8+j];
// B-frag: lane n=lane&15 holds W[k][n], k=(lane>>4)*8+j (pre-packed in ws);
// C/D: col=lane&15, row=(lane>>4)*4+reg.

#define NNODES 10000
#define NEDGES 160000

typedef unsigned short u16;
typedef unsigned int u32;
typedef short short8 __attribute__((ext_vector_type(8)));
typedef float f32x4 __attribute__((ext_vector_type(4)));

__device__ __forceinline__ float b2f(u16 u) {
  union { u32 i; float f; } v; v.i = ((u32)u) << 16; return v.f;
}
__device__ __forceinline__ u16 f2b(float f) {  // RNE (used for weights/features)
  union { float f; u32 i; } v; v.f = f;
  u32 r = v.i + 0x7FFFu + ((v.i >> 16) & 1u);
  return (u16)(r >> 16);
}
// pack two f32 -> dword of two truncated bf16 (lo in low half): 1 v_perm_b32
__device__ __forceinline__ u32 pk2(float lo, float hi) {
  return __builtin_amdgcn_perm(__float_as_uint(hi), __float_as_uint(lo), 0x07060302u);
}

#define INVF  0.02795084971874737f   // 1/sqrt(1280)
#define INV3  0.5773502691896258f    // 1/sqrt(3)
#define INV2  0.7071067811865476f    // 1/sqrt(2)

// ---- pack weights into MFMA B-frag order, bf16, scales folded ------------
// WSp u16[6nt][40kt][64lane][8j]; WVp u16[2nt][40kt][64lane][8j]
__global__ void pack_kernel(const float* __restrict__ W_ss, const float* __restrict__ W_vv_s,
                            const float* __restrict__ W_sv, const float* __restrict__ W_vs,
                            const float* __restrict__ W_vv_v,
                            u32* __restrict__ WSd, u32* __restrict__ WVd) {
  int t = blockIdx.x * 256 + threadIdx.x;
  if (t < 61440) {            // W_S dwords
    int d = t;
    int nt = d / 10240, r = d - nt * 10240;
    int kt = r >> 8, l = (r & 255) >> 2, jp = r & 3;
    int n = nt * 16 + (l & 15);
    int k0 = kt * 32 + ((l >> 4) << 3) + jp * 2;
    float f0, f1;
    f0 = (k0     < 1024) ? W_ss[k0 * 96 + n] * INVF       : W_vv_s[(k0 - 1024) * 96 + n] * (INVF * INV3);
    f1 = (k0 + 1 < 1024) ? W_ss[(k0 + 1) * 96 + n] * INVF : W_vv_s[(k0 - 1023) * 96 + n] * (INVF * INV3);
    WSd[d] = (u32)f2b(f0) | ((u32)f2b(f1) << 16);
  } else if (t < 81920) {     // W_V dwords
    int d = t - 61440;
    int nt = d / 10240, r = d - nt * 10240;
    int kt = r >> 8, l = (r & 255) >> 2, jp = r & 3;
    int n = nt * 16 + (l & 15);
    int k0 = kt * 32 + ((l >> 4) << 3) + jp * 2;
    float f[2];
#pragma unroll
    for (int jj = 0; jj < 2; jj++) {
      int k = k0 + jj;
      if (k < 512)       f[jj] = W_sv[k * 32 + n] * INVF;
      else if (k < 1024) f[jj] = W_vs[(k - 512) * 32 + n] * INVF;
      else               f[jj] = W_vv_v[(k - 1024) * 32 + n] * (INVF * INV2);
    }
    WVd[d] = (u32)f2b(f[0]) | ((u32)f2b(f[1]) << 16);
  }
}

__global__ void zero_kernel(float* __restrict__ p, int n) {
  int t = blockIdx.x * 256 + threadIdx.x;
  if (t < n) p[t] = 0.f;
}

// ---- edge kernel ---------------------------------------------------------
__global__ __launch_bounds__(256, 2) void edge_kernel(
    const float* __restrict__ x, const float* __restrict__ ea,
    const int* __restrict__ eidx,
    const u16* __restrict__ WSp, const u16* __restrict__ WVp,
    float* __restrict__ s_n, float* __restrict__ v_n) {
  __shared__ int idxL[64];
  __shared__ u16 s1b[64][64];
  __shared__ u16 v1b[64][96];
  __shared__ u16 s2b[64][16];
  __shared__ u16 v2b[64][24];
  __shared__ float gateL[64][32];
  __shared__ __align__(16) u16 Abuf[192 * 72];   // row stride 72 bf16 (144B)

  const int tid = threadIdx.x;
  const int eb = blockIdx.x * 64;
  if (tid < 64) idxL[tid] = eidx[eb + tid];
  __syncthreads();

  for (int t = tid; t < 64 * 160; t += 256) {
    int e = t / 160, j = t - e * 160;
    u16 v = f2b(x[(size_t)idxL[e] * 160 + j]);
    if (j < 64) s1b[e][j] = v; else v1b[e][j - 64] = v;
  }
  for (int t = tid; t < 64 * 40; t += 256) {
    int e = t / 40, j = t - e * 40;
    u16 v = f2b(ea[(eb + e) * 40 + j]);
    if (j < 16) s2b[e][j] = v; else v2b[e][j - 16] = v;
  }
  __syncthreads();

  const int eo = tid >> 2, q = tid & 3;          // build-role: edge, quarter
  const int wv = tid >> 6, lane = tid & 63;      // mfma-role
  const int ln = lane & 15, quad = lane >> 4;

  // hoist per-edge s2/v2 rows into registers (shared by 4 threads per edge)
  float s2f[16], v2f[24];
#pragma unroll
  for (int i = 0; i < 16; i++) s2f[i] = b2f(s2b[eo][i]);
#pragma unroll
  for (int i = 0; i < 24; i++) v2f[i] = b2f(v2b[eo][i]);

  // ================= S phase =================
  f32x4 aS[6];
#pragma unroll
  for (int i = 0; i < 6; i++) aS[i] = (f32x4){0.f, 0.f, 0.f, 0.f};

  for (int kc = 0; kc < 20; ++kc) {
    __syncthreads();
    u32* Ar = ((u32*)Abuf) + eo * 36;
    if (kc < 16) {                       // outer product s1 x s2
      int a = kc * 4 + q;
      float s1v = b2f(s1b[eo][a]);
      uint4 w0, w1;
      w0.x = pk2(s1v * s2f[0],  s1v * s2f[1]);
      w0.y = pk2(s1v * s2f[2],  s1v * s2f[3]);
      w0.z = pk2(s1v * s2f[4],  s1v * s2f[5]);
      w0.w = pk2(s1v * s2f[6],  s1v * s2f[7]);
      w1.x = pk2(s1v * s2f[8],  s1v * s2f[9]);
      w1.y = pk2(s1v * s2f[10], s1v * s2f[11]);
      w1.z = pk2(s1v * s2f[12], s1v * s2f[13]);
      w1.w = pk2(s1v * s2f[14], s1v * s2f[15]);
      ((uint4*)(Ar + q * 8))[0] = w0;
      ((uint4*)(Ar + q * 8))[1] = w1;
    } else {                             // dot3(v1,v2)
#pragma unroll
      for (int aa = 0; aa < 2; aa++) {
        int a = (kc - 16) * 8 + q * 2 + aa;
        const u16* vp = &v1b[eo][a * 3];
        float x0 = b2f(vp[0]), x1 = b2f(vp[1]), x2 = b2f(vp[2]);
        float d[8];
#pragma unroll
        for (int bb = 0; bb < 8; bb++)
          d[bb] = x0 * v2f[bb * 3] + x1 * v2f[bb * 3 + 1] + x2 * v2f[bb * 3 + 2];
        uint4 w;
        w.x = pk2(d[0], d[1]); w.y = pk2(d[2], d[3]);
        w.z = pk2(d[4], d[5]); w.w = pk2(d[6], d[7]);
        ((uint4*)(Ar + (q * 2 + aa) * 4))[0] = w;
      }
    }
    __syncthreads();
    const u16* Abase = Abuf + (wv * 16 + ln) * 72 + quad * 8;
#pragma unroll
    for (int ks = 0; ks < 2; ks++) {
      short8 af = *(const short8*)(Abase + ks * 32);
      int kt = kc * 2 + ks;
      const u16* Bb = WSp + ((size_t)kt * 64 + lane) * 8;
#pragma unroll
      for (int nt = 0; nt < 6; nt++) {
        short8 bf = *(const short8*)(Bb + nt * 20480);
        aS[nt] = __builtin_amdgcn_mfma_f32_16x16x32_bf16(af, bf, aS[nt], 0, 0, 0);
      }
    }
  }

  // S epilogue: silu -> atomics; sigmoid gates -> LDS
#pragma unroll
  for (int r = 0; r < 4; r++) {
    int e = wv * 16 + quad * 4 + r;
    int nid = idxL[e];
#pragma unroll
    for (int nt = 0; nt < 6; nt++) {
      float v = aS[nt][r];
      float sg = 1.f / (1.f + __expf(-v));
      if (nt < 4) atomicAdd(&s_n[nid * 64 + nt * 16 + ln], v * sg);
      else        gateL[e][(nt - 4) * 16 + ln] = sg;
    }
  }

  // ================= V phase =================
  f32x4 aV[3][2];
#pragma unroll
  for (int p = 0; p < 3; p++)
#pragma unroll
    for (int nt = 0; nt < 2; nt++) aV[p][nt] = (f32x4){0.f, 0.f, 0.f, 0.f};

  for (int kc = 0; kc < 20; ++kc) {
    __syncthreads();
    if (kc < 8) {                        // s1[a] * v2[b,p]
#pragma unroll
      for (int aa = 0; aa < 2; aa++) {
        int a = kc * 8 + q * 2 + aa;
        float s1v = b2f(s1b[eo][a]);
#pragma unroll
        for (int p = 0; p < 3; p++) {
          uint4 w;
          w.x = pk2(s1v * v2f[0 + p],  s1v * v2f[3 + p]);
          w.y = pk2(s1v * v2f[6 + p],  s1v * v2f[9 + p]);
          w.z = pk2(s1v * v2f[12 + p], s1v * v2f[15 + p]);
          w.w = pk2(s1v * v2f[18 + p], s1v * v2f[21 + p]);
          ((uint4*)(((u32*)Abuf) + (p * 64 + eo) * 36 + (q * 2 + aa) * 4))[0] = w;
        }
      }
    } else if (kc < 16) {                // v1[a,p] * s2[b]
      int a = (kc - 8) * 4 + q;
#pragma unroll
      for (int p = 0; p < 3; p++) {
        float v1v = b2f(v1b[eo][a * 3 + p]);
        uint4 w0, w1;
        w0.x = pk2(v1v * s2f[0],  v1v * s2f[1]);
        w0.y = pk2(v1v * s2f[2],  v1v * s2f[3]);
        w0.z = pk2(v1v * s2f[4],  v1v * s2f[5]);
        w0.w = pk2(v1v * s2f[6],  v1v * s2f[7]);
        w1.x = pk2(v1v * s2f[8],  v1v * s2f[9]);
        w1.y = pk2(v1v * s2f[10], v1v * s2f[11]);
        w1.z = pk2(v1v * s2f[12], v1v * s2f[13]);
        w1.w = pk2(v1v * s2f[14], v1v * s2f[15]);
        u32* Ar = ((u32*)Abuf) + (p * 64 + eo) * 36 + q * 8;
        ((uint4*)Ar)[0] = w0; ((uint4*)Ar)[1] = w1;
      }
    } else {                             // cross(v1[a], v2[b])[p]
#pragma unroll
      for (int aa = 0; aa < 2; aa++) {
        int a = (kc - 16) * 8 + q * 2 + aa;
        const u16* vp = &v1b[eo][a * 3];
        float vv[3] = { b2f(vp[0]), b2f(vp[1]), b2f(vp[2]) };
#pragma unroll
        for (int p = 0; p < 3; p++) {
          const int p1 = (p + 1) % 3, p2 = (p + 2) % 3;
          float d[8];
#pragma unroll
          for (int bb = 0; bb < 8; bb++)
            d[bb] = vv[p1] * v2f[bb * 3 + p2] - vv[p2] * v2f[bb * 3 + p1];
          uint4 w;
          w.x = pk2(d[0], d[1]); w.y = pk2(d[2], d[3]);
          w.z = pk2(d[4], d[5]); w.w = pk2(d[6], d[7]);
          ((uint4*)(((u32*)Abuf) + (p * 64 + eo) * 36 + (q * 2 + aa) * 4))[0] = w;
        }
      }
    }
    __syncthreads();
#pragma unroll
    for (int ks = 0; ks < 2; ks++) {
      int kt = kc * 2 + ks;
      short8 af[3];
#pragma unroll
      for (int p = 0; p < 3; p++)
        af[p] = *(const short8*)(Abuf + (p * 64 + wv * 16 + ln) * 72 + ks * 32 + quad * 8);
      const u16* Bb = WVp + ((size_t)kt * 64 + lane) * 8;
#pragma unroll
      for (int nt = 0; nt < 2; nt++) {
        short8 bf = *(const short8*)(Bb + nt * 20480);
#pragma unroll
        for (int p = 0; p < 3; p++)
          aV[p][nt] = __builtin_amdgcn_mfma_f32_16x16x32_bf16(af[p], bf, aV[p][nt], 0, 0, 0);
      }
    }
  }

  // V epilogue: gate + scatter
#pragma unroll
  for (int r = 0; r < 4; r++) {
    int e = wv * 16 + quad * 4 + r;
    int nid = idxL[e];
#pragma unroll
    for (int nt = 0; nt < 2; nt++) {
      int c = nt * 16 + ln;
      float g = gateL[e][c];
#pragma unroll
      for (int p = 0; p < 3; p++)
        atomicAdd(&v_n[nid * 96 + c * 3 + p], aV[p][nt][r] * g);
    }
  }
}

// ---- BN stats ------------------------------------------------------------
__global__ void stats_kernel(const float* __restrict__ s_n, const float* __restrict__ v_n,
                             float* __restrict__ stats) {
  int b = blockIdx.x, tid = threadIdx.x;
  int r0 = b * 100;
  int c = tid & 63, rg = tid >> 6;
  float s = 0.f, sq = 0.f;
  for (int r = r0 + rg; r < r0 + 100; r += 4) {
    float v = s_n[r * 64 + c];
    s += v; sq += v * v;
  }
  atomicAdd(&stats[c], s);
  atomicAdd(&stats[64 + c], sq);
  int c2 = tid & 31, rg2 = tid >> 5;
  float vn = 0.f;
  for (int r = r0 + rg2; r < r0 + 100; r += 8) {
    const float* vp = &v_n[r * 96 + c2 * 3];
    vn += vp[0] * vp[0] + vp[1] * vp[1] + vp[2] * vp[2];
  }
  atomicAdd(&stats[128 + c2], vn);
}

// ---- finalize ------------------------------------------------------------
__global__ void finalize_kernel(const float* __restrict__ s_n, const float* __restrict__ v_n,
                                const float* __restrict__ stats,
                                const float* __restrict__ x,
                                const float* __restrict__ bw_s, const float* __restrict__ bb_s,
                                const float* __restrict__ bw_v,
                                float* __restrict__ out) {
  int t = blockIdx.x * 256 + threadIdx.x;
  if (t >= NNODES * 160) return;
  int n = t / 160, j = t - n * 160;
  float xv = x[t];
  float r;
  if (j < 64) {
    float mu  = stats[j] * (1.f / NNODES);
    float var = stats[64 + j] * (1.f / NNODES) - mu * mu;
    var = fmaxf(var, 0.f);
    float v = s_n[n * 64 + j];
    r = (v - mu) * rsqrtf(var + 1e-5f) * bw_s[j] + bb_s[j];
  } else {
    int qq = j - 64;
    int c = qq / 3;
    float vn = stats[128 + c] * (1.f / (3.f * NNODES));
    float v = v_n[n * 96 + qq];
    r = v * rsqrtf(vn + 1e-5f) * bw_v[c];
  }
  out[t] = r + xv;
}

extern "C" void kernel_launch(void* const* d_in, const int* in_sizes, int n_in,
                              void* d_out, int out_size, void* d_ws, size_t ws_size,
                              hipStream_t stream) {
  const float* x      = (const float*)d_in[0];
  const float* ea     = (const float*)d_in[1];
  const float* W_ss   = (const float*)d_in[2];
  const float* W_vv_s = (const float*)d_in[3];
  const float* W_sv   = (const float*)d_in[4];
  const float* W_vs   = (const float*)d_in[5];
  const float* W_vv_v = (const float*)d_in[6];
  const float* bw_s   = (const float*)d_in[7];
  const float* bb_s   = (const float*)d_in[8];
  const float* bw_v   = (const float*)d_in[9];
  const int* eidx     = (const int*)d_in[10];
  float* out = (float*)d_out;

  u16* WSp     = (u16*)d_ws;              // 122880 u16
  u16* WVp     = WSp + 122880;            // 40960 u16
  float* s_n   = (float*)d_ws + 81920;    // 640000
  float* v_n   = s_n + 640000;            // 960000
  float* stats = v_n + 960000;            // 160

  pack_kernel<<<320, 256, 0, stream>>>(W_ss, W_vv_s, W_sv, W_vs, W_vv_v,
                                       (u32*)WSp, (u32*)WVp);
  zero_kernel<<<(1600160 + 255) / 256, 256, 0, stream>>>(s_n, 1600160);
  edge_kernel<<<NEDGES / 64, 256, 0, stream>>>(x, ea, eidx, WSp, WVp, s_n, v_n);
  stats_kernel<<<100, 256, 0, stream>>>(s_n, v_n, stats);
  finalize_kernel<<<(NNODES * 160 + 255) / 256, 256, 0, stream>>>(
      s_n, v_n, stats, x, bw_s, bb_s, bw_v, out);
}